// Round 2
// baseline (890.229 us; speedup 1.0000x reference)
//
#include <hip/hip_runtime.h>
#include <hip/hip_bf16.h>

#define BB 4
#define HH 16
#define LL 2048
#define DD 64
#define EE 1024
#define MM (BB*LL)   // 8192 rows

using bf16   = __hip_bfloat16;
using bf16x8 = __attribute__((ext_vector_type(8))) __bf16;
using f32x4  = __attribute__((ext_vector_type(4))) float;
using u32x4  = __attribute__((ext_vector_type(4))) unsigned int;

// ---- dtype-polymorphic helpers (bf16 vs fp32 inputs; RNE convert) ----
__device__ __forceinline__ bf16x8 ld8(const bf16* p){ return *(const bf16x8*)p; }
__device__ __forceinline__ bf16x8 ld8(const float* p){
  u32x4 a = *(const u32x4*)p;
  u32x4 b = *(const u32x4*)(p + 4);
  union { bf16x8 v; unsigned short s[8]; } r;
#pragma unroll
  for (int i = 0; i < 4; i++) r.s[i]     = (unsigned short)((a[i] + 0x7FFFu + ((a[i] >> 16) & 1u)) >> 16);
#pragma unroll
  for (int i = 0; i < 4; i++) r.s[i + 4] = (unsigned short)((b[i] + 0x7FFFu + ((b[i] >> 16) & 1u)) >> 16);
  return r.v;
}
__device__ __forceinline__ float ldf(const bf16* p){ return __bfloat162float(*p); }
__device__ __forceinline__ float ldf(const float* p){ return *p; }
__device__ __forceinline__ void stf(bf16* p, float v){ *p = __float2bfloat16(v); }
__device__ __forceinline__ void stf(float* p, float v){ *p = v; }
__device__ __forceinline__ bf16 to_b(bf16 v){ return v; }
__device__ __forceinline__ bf16 to_b(float v){ return __float2bfloat16(v); }

// ---- dtype detect: low 16 bits of each u32 word. bf16 data -> bf16 value with
// exponent field in a narrow band; fp32 data -> uniform mantissa bits (~16% in band).
__global__ __launch_bounds__(256) void detect_dtype(const unsigned int* __restrict__ w,
                                                    int* __restrict__ flag) {
  __shared__ int cnt[256];
  int tid = threadIdx.x;
  int c = 0;
  for (int i = 0; i < 16; i++) {
    unsigned u = w[tid * 16 + i];
    unsigned e = (u >> 7) & 0xFF;          // exponent field of the low bf16
    c += (e >= 100 && e <= 140) ? 1 : 0;
  }
  cnt[tid] = c;
  __syncthreads();
  for (int s = 128; s > 0; s >>= 1) {
    if (tid < s) cnt[tid] += cnt[tid + s];
    __syncthreads();
  }
  if (tid == 0) *flag = (cnt[0] > 2048) ? 1 : 0;   // 1 = bf16 inputs
}

// ---------------- weight transpose: Wt[n][k] = bf16(W[k][n]), 1024x1024 ----------------
template<typename T>
__device__ __forceinline__ void transpose_body(const T* __restrict__ W,
                                               bf16* __restrict__ Wt,
                                               bf16 (*t)[33]) {
  int tx = threadIdx.x, ty = threadIdx.y;            // block (32,8)
  int x = blockIdx.x * 32 + tx;                       // n
  for (int r = 0; r < 4; r++) {
    int y = blockIdx.y * 32 + ty + r * 8;             // k
    t[ty + r * 8][tx] = to_b(W[y * EE + x]);
  }
  __syncthreads();
  int x2 = blockIdx.y * 32 + tx;                      // k
  for (int r = 0; r < 4; r++) {
    int y2 = blockIdx.x * 32 + ty + r * 8;            // n
    Wt[y2 * EE + x2] = t[tx][ty + r * 8];
  }
}

__global__ __launch_bounds__(256) void transpose_w(const void* __restrict__ W,
                                                   bf16* __restrict__ Wt,
                                                   const int* __restrict__ flag) {
  __shared__ bf16 t[32][33];
  if (*flag) transpose_body<bf16>((const bf16*)W, Wt, t);
  else       transpose_body<float>((const float*)W, Wt, t);
}

// ---------------- 128x128-tile bf16 GEMM, Bt is [N][K] bf16 ----------------
// mode 0: C row-major [M][N] (dtype TD) + bias
// mode 1: C -> [B,H,L,D] bf16 + bias   (q/k head layout)
// mode 2: C -> [B,H,D,L] bf16 + bias   (v transposed head layout)
template<typename TA, typename TD>
__device__ void gemm_body(const TA* __restrict__ A, const bf16* __restrict__ Bt,
                          const TD* __restrict__ bias, void* __restrict__ Cv,
                          int mode, bf16* As, bf16* Bs) {
  constexpr int K = EE, N = EE;
  int tid = threadIdx.x;
  int lane = tid & 63, w = tid >> 6;
  int l16 = lane & 15, quad = lane >> 4;
  int m0 = blockIdx.y * 128;
  int n0 = blockIdx.x * 128;
  int mw = (w & 1) * 64;
  int nw = (w >> 1) * 64;

  f32x4 acc[4][4] = {};

  int r0 = tid >> 2, kc = (tid & 3) * 8;   // staging chunk (row, k-offset)
  int r1 = r0 + 64;

  for (int k0 = 0; k0 < K; k0 += 32) {
    __syncthreads();
    *(bf16x8*)(As + r0 * 40 + kc) = ld8(A + (size_t)(m0 + r0) * K + k0 + kc);
    *(bf16x8*)(As + r1 * 40 + kc) = ld8(A + (size_t)(m0 + r1) * K + k0 + kc);
    *(bf16x8*)(Bs + r0 * 40 + kc) = ld8(Bt + (size_t)(n0 + r0) * K + k0 + kc);
    *(bf16x8*)(Bs + r1 * 40 + kc) = ld8(Bt + (size_t)(n0 + r1) * K + k0 + kc);
    __syncthreads();
    bf16x8 af[4], bfr[4];
    for (int t = 0; t < 4; t++) {
      af[t]  = *(const bf16x8*)(As + (mw + t * 16 + l16) * 40 + quad * 8);
      bfr[t] = *(const bf16x8*)(Bs + (nw + t * 16 + l16) * 40 + quad * 8);
    }
    for (int mt = 0; mt < 4; mt++)
      for (int nt = 0; nt < 4; nt++)
        acc[mt][nt] = __builtin_amdgcn_mfma_f32_16x16x32_bf16(af[mt], bfr[nt], acc[mt][nt], 0, 0, 0);
  }

  for (int nt = 0; nt < 4; nt++) {
    int col = n0 + nw + nt * 16 + l16;
    float bv = ldf(bias + col);
    int h = col >> 6, d = col & 63;
    for (int mt = 0; mt < 4; mt++) {
      f32x4 v = acc[mt][nt];
      int rowb = m0 + mw + mt * 16 + quad * 4;
      for (int i = 0; i < 4; i++) {
        int row = rowb + i;
        float val = v[i] + bv;
        if (mode == 0) {
          stf(((TD*)Cv) + (size_t)row * N + col, val);
        } else {
          bf16* C = (bf16*)Cv;
          int b = row >> 11, l = row & 2047;
          size_t base = (size_t)(b * HH + h) * (LL * DD);
          if (mode == 1) C[base + (size_t)l * DD + d] = __float2bfloat16(val);
          else           C[base + (size_t)d * LL + l] = __float2bfloat16(val);
        }
      }
    }
  }
}

__global__ __launch_bounds__(256) void qkv_gemm(
    const void* __restrict__ Q, const void* __restrict__ Kin, const void* __restrict__ V,
    const bf16* __restrict__ WQt, const bf16* __restrict__ WKt, const bf16* __restrict__ WVt,
    const void* __restrict__ bQ, const void* __restrict__ bK, const void* __restrict__ bV,
    bf16* __restrict__ qo, bf16* __restrict__ ko, bf16* __restrict__ vo,
    const int* __restrict__ flag) {
  __shared__ __align__(16) bf16 As[128 * 40];
  __shared__ __align__(16) bf16 Bs[128 * 40];
  int z = blockIdx.z;
  const void* A    = (z == 0) ? Q   : (z == 1) ? Kin : V;
  const bf16* Bt   = (z == 0) ? WQt : (z == 1) ? WKt : WVt;
  const void* bb   = (z == 0) ? bQ  : (z == 1) ? bK  : bV;
  bf16* C          = (z == 0) ? qo  : (z == 1) ? ko  : vo;
  int mode = (z == 2) ? 2 : 1;
  if (*flag) gemm_body<bf16, bf16>((const bf16*)A, Bt, (const bf16*)bb, C, mode, As, Bs);
  else       gemm_body<float, float>((const float*)A, Bt, (const float*)bb, C, mode, As, Bs);
}

__global__ __launch_bounds__(256) void out_gemm(const bf16* __restrict__ A,
                                                const bf16* __restrict__ WOt,
                                                const void* __restrict__ bO,
                                                void* __restrict__ C,
                                                const int* __restrict__ flag) {
  __shared__ __align__(16) bf16 As[128 * 40];
  __shared__ __align__(16) bf16 Bs[128 * 40];
  if (*flag) gemm_body<bf16, bf16>(A, WOt, (const bf16*)bO, C, 0, As, Bs);
  else       gemm_body<bf16, float>(A, WOt, (const float*)bO, C, 0, As, Bs);
}

// ---------------- flash attention, causal ----------------
// q,k: [B,H,L,D]  v: [B,H,D,L]  out: [B,L,E]  (all bf16 workspace)
#define MASKV (-1.0e30f)
__global__ __launch_bounds__(256) void attn(const bf16* __restrict__ qg,
                                            const bf16* __restrict__ kg,
                                            const bf16* __restrict__ vg,
                                            bf16* __restrict__ outg) {
  int bh = blockIdx.y;
  int qb = blockIdx.x;
  int tid = threadIdx.x;
  int w = tid >> 6, lane = tid & 63, l16 = lane & 15, quad = lane >> 4;

  const bf16* qp = qg + (size_t)bh * LL * DD;
  const bf16* kp = kg + (size_t)bh * LL * DD;
  const bf16* vp = vg + (size_t)bh * DD * LL;

  int qrow0 = qb * 64 + w * 16;      // this wave's 16 q-rows
  bf16x8 aq0 = *(const bf16x8*)(qp + (size_t)(qrow0 + l16) * DD + quad * 8);
  bf16x8 aq1 = *(const bf16x8*)(qp + (size_t)(qrow0 + l16) * DD + 32 + quad * 8);

  float m_i[4], l_i[4];
  f32x4 o[4] = {};
  for (int i = 0; i < 4; i++) { m_i[i] = MASKV; l_i[i] = 0.f; }

  __shared__ __align__(16) bf16 P[4][16 * 40];   // per-wave P tile, padded rows
  bf16* Pw = &P[w][0];

  const f32x4 z4 = {};
  int kb_end = (qrow0 + 16 + 31) >> 5;           // per-wave causal trip count
  for (int kb = 0; kb < kb_end; kb++) {
    int kbase = kb * 32;
    const bf16* kr0 = kp + (size_t)(kbase + l16) * DD + quad * 8;
    const bf16* kr1 = kr0 + 16 * DD;
    bf16x8 b00 = *(const bf16x8*)(kr0);
    bf16x8 b01 = *(const bf16x8*)(kr0 + 32);
    bf16x8 b10 = *(const bf16x8*)(kr1);
    bf16x8 b11 = *(const bf16x8*)(kr1 + 32);
    f32x4 s0 = __builtin_amdgcn_mfma_f32_16x16x32_bf16(aq0, b00, z4, 0, 0, 0);
    s0       = __builtin_amdgcn_mfma_f32_16x16x32_bf16(aq1, b01, s0, 0, 0, 0);
    f32x4 s1 = __builtin_amdgcn_mfma_f32_16x16x32_bf16(aq0, b10, z4, 0, 0, 0);
    s1       = __builtin_amdgcn_mfma_f32_16x16x32_bf16(aq1, b11, s1, 0, 0, 0);

    int c0 = kbase + l16, c1 = kbase + 16 + l16;
    int rbase = qrow0 + quad * 4;
    float pv0[4], pv1[4];
    for (int i = 0; i < 4; i++) {
      int r = rbase + i;
      float sc0 = (c0 <= r) ? s0[i] * 0.125f : MASKV;
      float sc1 = (c1 <= r) ? s1[i] * 0.125f : MASKV;
      float mx = fmaxf(sc0, sc1);
      for (int off = 1; off < 16; off <<= 1) mx = fmaxf(mx, __shfl_xor(mx, off));
      float mnew = fmaxf(m_i[i], mx);
      float al = exp2f((m_i[i] - mnew) * 1.44269504f);
      float p0 = exp2f((sc0 - mnew) * 1.44269504f);
      float p1 = exp2f((sc1 - mnew) * 1.44269504f);
      float ps = p0 + p1;
      for (int off = 1; off < 16; off <<= 1) ps += __shfl_xor(ps, off);
      l_i[i] = l_i[i] * al + ps;
      m_i[i] = mnew;
      o[0][i] *= al; o[1][i] *= al; o[2][i] *= al; o[3][i] *= al;
      pv0[i] = p0; pv1[i] = p1;
    }
    for (int i = 0; i < 4; i++) {
      Pw[(quad * 4 + i) * 40 + l16]      = __float2bfloat16(pv0[i]);
      Pw[(quad * 4 + i) * 40 + 16 + l16] = __float2bfloat16(pv1[i]);
    }
    asm volatile("s_waitcnt lgkmcnt(0)" ::: "memory");  // wave-internal LDS RAW
    bf16x8 ap = *(const bf16x8*)(Pw + l16 * 40 + quad * 8);
    for (int j = 0; j < 4; j++) {
      bf16x8 vb = *(const bf16x8*)(vp + (size_t)(j * 16 + l16) * LL + kbase + quad * 8);
      o[j] = __builtin_amdgcn_mfma_f32_16x16x32_bf16(ap, vb, o[j], 0, 0, 0);
    }
  }

  int b = bh >> 4, h = bh & 15;
  for (int j = 0; j < 4; j++) {
    for (int i = 0; i < 4; i++) {
      float val = o[j][i] / l_i[i];
      int row = qrow0 + quad * 4 + i;
      outg[(size_t)(b * LL + row) * EE + h * DD + j * 16 + l16] = __float2bfloat16(val);
    }
  }
}

extern "C" void kernel_launch(void* const* d_in, const int* in_sizes, int n_in,
                              void* d_out, int out_size, void* d_ws, size_t ws_size,
                              hipStream_t stream) {
  const void* Q   = d_in[0];
  const void* Kin = d_in[1];
  const void* V   = d_in[2];
  const void* WQ  = d_in[3];
  const void* bQ  = d_in[4];
  const void* WK  = d_in[5];
  const void* bK  = d_in[6];
  const void* WV  = d_in[7];
  const void* bV  = d_in[8];
  const void* WO  = d_in[9];
  const void* bO  = d_in[10];

  int* flag = (int*)d_ws;
  bf16* base = (bf16*)((char*)d_ws + 256);
  bf16* wqt  = base;                        // 4 x 1024^2 bf16
  bf16* wkt  = wqt + (size_t)EE * EE;
  bf16* wvt  = wkt + (size_t)EE * EE;
  bf16* wot  = wvt + (size_t)EE * EE;
  bf16* qws  = wot + (size_t)EE * EE;       // [B,H,L,D]
  bf16* kws  = qws + (size_t)MM * EE;       // [B,H,L,D]
  bf16* vws  = kws + (size_t)MM * EE;       // [B,H,D,L]
  bf16* aout = vws + (size_t)MM * EE;       // [B,L,E]

  detect_dtype<<<1, 256, 0, stream>>>((const unsigned int*)WQ, flag);

  dim3 tb(32, 8);
  dim3 tg(EE / 32, EE / 32);
  transpose_w<<<tg, tb, 0, stream>>>(WQ, wqt, flag);
  transpose_w<<<tg, tb, 0, stream>>>(WK, wkt, flag);
  transpose_w<<<tg, tb, 0, stream>>>(WV, wvt, flag);
  transpose_w<<<tg, tb, 0, stream>>>(WO, wot, flag);

  dim3 gg(EE / 128, MM / 128, 3);
  qkv_gemm<<<gg, 256, 0, stream>>>(Q, Kin, V, wqt, wkt, wvt, bQ, bK, bV, qws, kws, vws, flag);

  attn<<<dim3(LL / 64, BB * HH), 256, 0, stream>>>(qws, kws, vws, aout);

  out_gemm<<<dim3(EE / 128, MM / 128), 256, 0, stream>>>(aout, wot, bO, d_out, flag);
}

// Round 4
// 787.001 us; speedup vs baseline: 1.1312x; 1.1312x over previous
//
#include <hip/hip_runtime.h>
#include <hip/hip_bf16.h>

#define BB 4
#define HH 16
#define LL 2048
#define DD 64
#define EE 1024
#define MM (BB*LL)   // 8192 rows
#define SCL 0.125f
#define L2E 1.44269504f

using bf16   = __hip_bfloat16;
using bf16x8 = __attribute__((ext_vector_type(8))) __bf16;
using s16x4  = __attribute__((ext_vector_type(4))) short;
using f32x4  = __attribute__((ext_vector_type(4))) float;
using u32x4  = __attribute__((ext_vector_type(4))) unsigned int;
typedef unsigned int u32;

// ---- dtype-polymorphic helpers (verified in R2) ----
__device__ __forceinline__ bf16x8 ld8(const bf16* p){ return *(const bf16x8*)p; }
__device__ __forceinline__ bf16x8 ld8(const float* p){
  u32x4 a = *(const u32x4*)p;
  u32x4 b = *(const u32x4*)(p + 4);
  union { bf16x8 v; unsigned short s[8]; } r;
#pragma unroll
  for (int i = 0; i < 4; i++) r.s[i]     = (unsigned short)((a[i] + 0x7FFFu + ((a[i] >> 16) & 1u)) >> 16);
#pragma unroll
  for (int i = 0; i < 4; i++) r.s[i + 4] = (unsigned short)((b[i] + 0x7FFFu + ((b[i] >> 16) & 1u)) >> 16);
  return r.v;
}
__device__ __forceinline__ float ldf(const bf16* p){ return __bfloat162float(*p); }
__device__ __forceinline__ float ldf(const float* p){ return *p; }
__device__ __forceinline__ bf16 to_b(bf16 v){ return v; }
__device__ __forceinline__ bf16 to_b(float v){ return __float2bfloat16(v); }

// async global->LDS, 16B/lane; LDS dest = wave-uniform base + lane*16 (m97/m104)
__device__ __forceinline__ void async16(const bf16* g, bf16* l) {
  __builtin_amdgcn_global_load_lds((const __attribute__((address_space(1))) u32*)g,
                                   (__attribute__((address_space(3))) u32*)l, 16, 0, 0);
}

// ---- dtype detect (verified in R2): low 16 bits of each u32 word ----
__global__ __launch_bounds__(256) void detect_dtype(const unsigned int* __restrict__ w,
                                                    int* __restrict__ flag) {
  __shared__ int cnt[256];
  int tid = threadIdx.x;
  int c = 0;
  for (int i = 0; i < 16; i++) {
    unsigned u = w[tid * 16 + i];
    unsigned e = (u >> 7) & 0xFF;
    c += (e >= 100 && e <= 140) ? 1 : 0;
  }
  cnt[tid] = c;
  __syncthreads();
  for (int s = 128; s > 0; s >>= 1) {
    if (tid < s) cnt[tid] += cnt[tid + s];
    __syncthreads();
  }
  if (tid == 0) *flag = (cnt[0] > 2048) ? 1 : 0;   // 1 = bf16 inputs
}

// ---------------- fused weight transposes: Wt[n][k] = bf16(W[k][n]) ----------------
template<typename T>
__device__ __forceinline__ void tr_body(const T* __restrict__ W, bf16* __restrict__ Wt,
                                        bf16 (*t)[33]) {
  int tx = threadIdx.x, ty = threadIdx.y;            // block (32,8)
  int x = blockIdx.x * 32 + tx;
  for (int r = 0; r < 4; r++)
    t[ty + r * 8][tx] = to_b(W[(blockIdx.y * 32 + ty + r * 8) * EE + x]);
  __syncthreads();
  int x2 = blockIdx.y * 32 + tx;
  for (int r = 0; r < 4; r++)
    Wt[(blockIdx.x * 32 + ty + r * 8) * EE + x2] = t[tx][ty + r * 8];
}

__global__ __launch_bounds__(256) void transpose_w4(
    const void* __restrict__ W0, const void* __restrict__ W1,
    const void* __restrict__ W2, const void* __restrict__ W3,
    bf16* __restrict__ T0, bf16* __restrict__ T1,
    bf16* __restrict__ T2, bf16* __restrict__ T3,
    const int* __restrict__ flag) {
  __shared__ bf16 t[32][33];
  int z = blockIdx.z;
  const void* W = (z == 0) ? W0 : (z == 1) ? W1 : (z == 2) ? W2 : W3;
  bf16* Wt      = (z == 0) ? T0 : (z == 1) ? T1 : (z == 2) ? T2 : T3;
  if (*flag) tr_body<bf16>((const bf16*)W, Wt, t);
  else       tr_body<float>((const float*)W, Wt, t);
}

// ---------------- m97-style 128x128 GEMM, Bt is [N][K] bf16 ----------------
// mode 0: C bf16 row-major [M][E] + bias        (q/k projections -> workspace)
// mode 2: C bf16 [B,H,D,L] + bias               (v transposed head layout)
// mode 3: C TIO row-major [M][E] + bias         (final output)
// TA: A dtype. bf16 -> async16 staging; float -> VALU convert staging.
template<typename TA, typename TIO>
__device__ void gemm_body(const TA* __restrict__ A, const bf16* __restrict__ Bt,
                          const TIO* __restrict__ bias, void* __restrict__ Cv,
                          int mode, bf16* As, bf16* Bs) {
  constexpr int K = EE;
  int tid = threadIdx.x;
  int lane = tid & 63, w = tid >> 6;
  int l16 = lane & 15, quad = lane >> 4;
  int m0 = blockIdx.y * 128;
  int n0 = blockIdx.x * 128;
  int mw = (w & 1) * 64;
  int nw = (w >> 1) * 64;
  int lr = lane >> 2;            // staging row within 16-row group
  int lc = (lane & 3) * 8;       // staging col (elements)

  f32x4 acc[4][4] = {};

  for (int k0 = 0; k0 < K; k0 += 32) {
    __syncthreads();
#pragma unroll
    for (int s = 0; s < 2; s++) {
      int r = w * 32 + s * 16;
      if constexpr (__is_same(TA, bf16)) {
        async16(A + (size_t)(m0 + r + lr) * K + k0 + lc, As + r * 32);
      } else {
        *(bf16x8*)(As + (r + lr) * 32 + lc) = ld8(A + (size_t)(m0 + r + lr) * K + k0 + lc);
      }
      async16(Bt + (size_t)(n0 + r + lr) * K + k0 + lc, Bs + r * 32);
    }
    __syncthreads();   // drains vmcnt+lgkmcnt before barrier (m97)
    bf16x8 af[4], bfr[4];
#pragma unroll
    for (int t = 0; t < 4; t++) {
      af[t]  = *(const bf16x8*)(As + (mw + t * 16 + l16) * 32 + quad * 8);
      bfr[t] = *(const bf16x8*)(Bs + (nw + t * 16 + l16) * 32 + quad * 8);
    }
#pragma unroll
    for (int mt = 0; mt < 4; mt++)
#pragma unroll
      for (int nt = 0; nt < 4; nt++)
        acc[mt][nt] = __builtin_amdgcn_mfma_f32_16x16x32_bf16(af[mt], bfr[nt], acc[mt][nt], 0, 0, 0);
  }

#pragma unroll
  for (int nt = 0; nt < 4; nt++) {
    int col = n0 + nw + nt * 16 + l16;
    float bv = ldf(bias + col);
    int hh = col >> 6, d = col & 63;
#pragma unroll
    for (int mt = 0; mt < 4; mt++) {
      f32x4 v = acc[mt][nt];
      int rowb = m0 + mw + mt * 16 + quad * 4;
      if (mode == 0) {
#pragma unroll
        for (int i = 0; i < 4; i++)
          ((bf16*)Cv)[(size_t)(rowb + i) * EE + col] = __float2bfloat16(v[i] + bv);
      } else if (mode == 3) {
#pragma unroll
        for (int i = 0; i < 4; i++) {
          float val = v[i] + bv;
          if constexpr (__is_same(TIO, bf16))
            ((bf16*)Cv)[(size_t)(rowb + i) * EE + col] = __float2bfloat16(val);
          else
            ((float*)Cv)[(size_t)(rowb + i) * EE + col] = val;
        }
      } else {  // mode 2: V^T [B,H,D,L], 4 consecutive l -> 8B store
        int b = rowb >> 11, l0 = rowb & 2047;
        union { s16x4 p; bf16 e[4]; } u;
#pragma unroll
        for (int i = 0; i < 4; i++) u.e[i] = __float2bfloat16(v[i] + bv);
        *(s16x4*)((bf16*)Cv + ((size_t)(b * HH + hh) * DD + d) * LL + l0) = u.p;
      }
    }
  }
}

__global__ __launch_bounds__(256) void qkv_gemm(
    const void* __restrict__ Q, const void* __restrict__ Kin, const void* __restrict__ V,
    const bf16* __restrict__ WQt, const bf16* __restrict__ WKt, const bf16* __restrict__ WVt,
    const void* __restrict__ bQ, const void* __restrict__ bK, const void* __restrict__ bV,
    bf16* __restrict__ qo, bf16* __restrict__ ko, bf16* __restrict__ vo,
    const int* __restrict__ flag) {
  __shared__ __align__(16) bf16 As[128 * 32];
  __shared__ __align__(16) bf16 Bs[128 * 32];
  int z = blockIdx.z;
  const void* A    = (z == 0) ? Q   : (z == 1) ? Kin : V;
  const bf16* Bt   = (z == 0) ? WQt : (z == 1) ? WKt : WVt;
  const void* bb   = (z == 0) ? bQ  : (z == 1) ? bK  : bV;
  bf16* C          = (z == 0) ? qo  : (z == 1) ? ko  : vo;
  int mode = (z == 2) ? 2 : 0;
  if (*flag) gemm_body<bf16, bf16>((const bf16*)A, Bt, (const bf16*)bb, C, mode, As, Bs);
  else       gemm_body<float, float>((const float*)A, Bt, (const float*)bb, C, mode, As, Bs);
}

__global__ __launch_bounds__(256) void out_gemm(const bf16* __restrict__ A,
                                                const bf16* __restrict__ WOt,
                                                const void* __restrict__ bO,
                                                void* __restrict__ C,
                                                const int* __restrict__ flag) {
  __shared__ __align__(16) bf16 As[128 * 32];
  __shared__ __align__(16) bf16 Bs[128 * 32];
  if (*flag) gemm_body<bf16, bf16>(A, WOt, (const bf16*)bO, C, 3, As, Bs);
  else       gemm_body<bf16, float>(A, WOt, (const float*)bO, C, 3, As, Bs);
}

// ---------------- flash attention, causal, S^T formulation ----------------
// q,k: [B,L,E] bf16 (head offset h*64, row stride E)   v: [B,H,D,L] bf16   out: [B,L,E] bf16
__global__ __launch_bounds__(256) void attn(const bf16* __restrict__ qg,
                                            const bf16* __restrict__ kg,
                                            const bf16* __restrict__ vg,
                                            bf16* __restrict__ outg) {
  int bh = blockIdx.y;
  int pb = blockIdx.x;               // handles tiles pb and 31-pb (causal load balance)
  int tid = threadIdx.x;
  int w = tid >> 6, lane = tid & 63, l16 = lane & 15, quad = lane >> 4;
  int b = bh >> 4, hh = bh & 15;

  const bf16* qp = qg + (size_t)b * LL * EE + hh * DD;
  const bf16* kp = kg + (size_t)b * LL * EE + hh * DD;
  const bf16* vp = vg + (size_t)bh * DD * LL;
  const f32x4 z4 = {};

  for (int half = 0; half < 2; half++) {
    int tile = half ? (31 - pb) : pb;
    int qrow0 = tile * 64 + w * 16;
    int q = qrow0 + l16;
    bf16x8 bq0 = *(const bf16x8*)(qp + (size_t)q * EE + quad * 8);
    bf16x8 bq1 = *(const bf16x8*)(qp + (size_t)q * EE + 32 + quad * 8);

    float m = -1.0e30f, l = 0.f;
    f32x4 o[4] = {};

    int kb_end = (qrow0 + 16 + 63) >> 6;
    for (int kb = 0; kb < kb_end; kb++) {
      int kbase = kb * 64;
      // ---- S^T = K·Q^T: A = K rows, B = Q rows; C frag: row=key, col=q ----
      f32x4 s[4];
#pragma unroll
      for (int kt = 0; kt < 4; kt++) {
        const bf16* kr = kp + (size_t)(kbase + kt * 16 + l16) * EE + quad * 8;
        bf16x8 kf0 = *(const bf16x8*)(kr);
        bf16x8 kf1 = *(const bf16x8*)(kr + 32);
        s[kt] = __builtin_amdgcn_mfma_f32_16x16x32_bf16(kf0, bq0, z4, 0, 0, 0);
        s[kt] = __builtin_amdgcn_mfma_f32_16x16x32_bf16(kf1, bq1, s[kt], 0, 0, 0);
      }
#if __has_builtin(__builtin_amdgcn_mfma_f32_16x16x16bf16_1k)
      s16x4 vf[4][4];   // V^T A-frags: A[m=d=l16][k=key=quad*4+j]
#pragma unroll
      for (int j = 0; j < 4; j++)
#pragma unroll
        for (int kt = 0; kt < 4; kt++)
          vf[j][kt] = *(const s16x4*)(vp + (size_t)(j * 16 + l16) * LL + kbase + kt * 16 + quad * 4);
#endif
      // ---- mask + scale ----
      float sv[16];
      if (kbase + 63 <= qrow0) {
#pragma unroll
        for (int kt = 0; kt < 4; kt++)
#pragma unroll
          for (int i = 0; i < 4; i++) sv[kt * 4 + i] = s[kt][i] * SCL;
      } else {
        int rel = q - kbase - quad * 4;
#pragma unroll
        for (int kt = 0; kt < 4; kt++)
#pragma unroll
          for (int i = 0; i < 4; i++)
            sv[kt * 4 + i] = (kt * 16 + i <= rel) ? s[kt][i] * SCL : -1.0e30f;
      }
      // ---- online softmax (per lane = per q column; 2 cross-quad shuffles) ----
      float mloc = sv[0];
#pragma unroll
      for (int i = 1; i < 16; i++) mloc = fmaxf(mloc, sv[i]);
      mloc = fmaxf(mloc, __shfl_xor(mloc, 16));
      mloc = fmaxf(mloc, __shfl_xor(mloc, 32));
      float mnew = fmaxf(m, mloc);
      float alpha = exp2f((m - mnew) * L2E);
      float p[16], ssum = 0.f;
#pragma unroll
      for (int i = 0; i < 16; i++) { p[i] = exp2f((sv[i] - mnew) * L2E); ssum += p[i]; }
      ssum += __shfl_xor(ssum, 16);
      ssum += __shfl_xor(ssum, 32);
      l = l * alpha + ssum;
      m = mnew;
#pragma unroll
      for (int j = 0; j < 4; j++)
#pragma unroll
        for (int i = 0; i < 4; i++) o[j][i] *= alpha;
      // ---- P^T pack: C-layout == B-operand layout of 16x16x16 MFMA ----
      union { s16x4 v4; bf16 e[4]; unsigned u[2]; } pk[4];
#pragma unroll
      for (int kt = 0; kt < 4; kt++)
#pragma unroll
        for (int i = 0; i < 4; i++) pk[kt].e[i] = __float2bfloat16(p[kt * 4 + i]);
#if __has_builtin(__builtin_amdgcn_mfma_f32_16x16x16bf16_1k)
#pragma unroll
      for (int kt = 0; kt < 4; kt++)
#pragma unroll
        for (int j = 0; j < 4; j++)
          o[j] = __builtin_amdgcn_mfma_f32_16x16x16bf16_1k(vf[j][kt], pk[kt].v4, o[j], 0, 0, 0);
#else
#pragma unroll
      for (int c = 0; c < 2; c++) {
        union { bf16x8 v8; unsigned u[4]; } bfr;
#pragma unroll
        for (int r = 0; r < 4; r++) {
          int key = c * 32 + quad * 8 + 2 * r;
          int srcl = (((key >> 2) & 3) << 4) + l16;
          unsigned v0 = __shfl((int)pk[2 * c].u[r & 1], srcl, 64);
          unsigned v1 = __shfl((int)pk[2 * c + 1].u[r & 1], srcl, 64);
          bfr.u[r] = (quad < 2) ? v0 : v1;
        }
#pragma unroll
        for (int j = 0; j < 4; j++) {
          bf16x8 vfr = *(const bf16x8*)(vp + (size_t)(j * 16 + l16) * LL + kbase + c * 32 + quad * 8);
          o[j] = __builtin_amdgcn_mfma_f32_16x16x32_bf16(vfr, bfr.v8, o[j], 0, 0, 0);
        }
      }
#endif
    }
    // ---- epilogue: O^T frag (d = j*16+quad*4+i, q = l16), 8B packed stores ----
    float inv = 1.0f / l;
#pragma unroll
    for (int j = 0; j < 4; j++) {
      union { s16x4 v4; bf16 e[4]; } u;
#pragma unroll
      for (int i = 0; i < 4; i++) u.e[i] = __float2bfloat16(o[j][i] * inv);
      *(s16x4*)(outg + (size_t)(b * LL + q) * EE + hh * DD + j * 16 + quad * 4) = u.v4;
    }
  }
}

extern "C" void kernel_launch(void* const* d_in, const int* in_sizes, int n_in,
                              void* d_out, int out_size, void* d_ws, size_t ws_size,
                              hipStream_t stream) {
  const void* Q   = d_in[0];
  const void* Kin = d_in[1];
  const void* V   = d_in[2];
  const void* WQ  = d_in[3];
  const void* bQ  = d_in[4];
  const void* WK  = d_in[5];
  const void* bK  = d_in[6];
  const void* WV  = d_in[7];
  const void* bV  = d_in[8];
  const void* WO  = d_in[9];
  const void* bO  = d_in[10];

  int* flag = (int*)d_ws;
  bf16* base = (bf16*)((char*)d_ws + 256);
  bf16* wqt  = base;                        // 4 x 1024^2 bf16
  bf16* wkt  = wqt + (size_t)EE * EE;
  bf16* wvt  = wkt + (size_t)EE * EE;
  bf16* wot  = wvt + (size_t)EE * EE;
  bf16* qws  = wot + (size_t)EE * EE;       // [B,L,E]
  bf16* kws  = qws + (size_t)MM * EE;       // [B,L,E]
  bf16* vws  = kws + (size_t)MM * EE;       // [B,H,D,L]
  bf16* aout = vws + (size_t)MM * EE;       // [B,L,E]

  detect_dtype<<<1, 256, 0, stream>>>((const unsigned int*)WQ, flag);

  transpose_w4<<<dim3(32, 32, 4), dim3(32, 8), 0, stream>>>(
      WQ, WK, WV, WO, wqt, wkt, wvt, wot, flag);

  qkv_gemm<<<dim3(EE / 128, MM / 128, 3), 256, 0, stream>>>(
      Q, Kin, V, wqt, wkt, wvt, bQ, bK, bV, qws, kws, vws, flag);

  attn<<<dim3(16, BB * HH), 256, 0, stream>>>(qws, kws, vws, aout);

  out_gemm<<<dim3(EE / 128, MM / 128), 256, 0, stream>>>(aout, wot, bO, d_out, flag);
}

// Round 5
// 453.670 us; speedup vs baseline: 1.9623x; 1.7347x over previous
//
#include <hip/hip_runtime.h>
#include <hip/hip_bf16.h>

#define BB 4
#define HH 16
#define LL 2048
#define DD 64
#define EE 1024
#define MM (BB*LL)   // 8192 rows
#define SCL 0.125f
#define L2E 1.44269504f

using bf16   = __hip_bfloat16;
using bf16x8 = __attribute__((ext_vector_type(8))) __bf16;
using s16x4  = __attribute__((ext_vector_type(4))) short;
using f32x4  = __attribute__((ext_vector_type(4))) float;
using u32x4  = __attribute__((ext_vector_type(4))) unsigned int;
typedef unsigned int u32;

// ---- dtype-polymorphic helpers (verified R2/R4) ----
__device__ __forceinline__ bf16x8 ld8(const bf16* p){ return *(const bf16x8*)p; }
__device__ __forceinline__ bf16x8 ld8(const float* p){
  u32x4 a = *(const u32x4*)p;
  u32x4 b = *(const u32x4*)(p + 4);
  union { bf16x8 v; unsigned short s[8]; } r;
#pragma unroll
  for (int i = 0; i < 4; i++) r.s[i]     = (unsigned short)((a[i] + 0x7FFFu + ((a[i] >> 16) & 1u)) >> 16);
#pragma unroll
  for (int i = 0; i < 4; i++) r.s[i + 4] = (unsigned short)((b[i] + 0x7FFFu + ((b[i] >> 16) & 1u)) >> 16);
  return r.v;
}
__device__ __forceinline__ float ldf(const bf16* p){ return __bfloat162float(*p); }
__device__ __forceinline__ float ldf(const float* p){ return *p; }
__device__ __forceinline__ bf16 to_b(bf16 v){ return v; }
__device__ __forceinline__ bf16 to_b(float v){ return __float2bfloat16(v); }

// async global->LDS, 16B/lane; LDS dest = wave-uniform base + lane*16 (m97/m104)
__device__ __forceinline__ void async16(const bf16* g, bf16* l) {
  __builtin_amdgcn_global_load_lds((const __attribute__((address_space(1))) u32*)g,
                                   (__attribute__((address_space(3))) u32*)l, 16, 0, 0);
}

// ---- dtype detect (verified R2/R4) ----
__global__ __launch_bounds__(256) void detect_dtype(const unsigned int* __restrict__ w,
                                                    int* __restrict__ flag) {
  __shared__ int cnt[256];
  int tid = threadIdx.x;
  int c = 0;
  for (int i = 0; i < 16; i++) {
    unsigned u = w[tid * 16 + i];
    unsigned e = (u >> 7) & 0xFF;
    c += (e >= 100 && e <= 140) ? 1 : 0;
  }
  cnt[tid] = c;
  __syncthreads();
  for (int s = 128; s > 0; s >>= 1) {
    if (tid < s) cnt[tid] += cnt[tid + s];
    __syncthreads();
  }
  if (tid == 0) *flag = (cnt[0] > 2048) ? 1 : 0;   // 1 = bf16 inputs
}

// ---- input pre-convert: Q/K/V -> bf16 workspace (copy if already bf16) ----
__global__ __launch_bounds__(256) void convert_in(
    const void* __restrict__ X0, const void* __restrict__ X1, const void* __restrict__ X2,
    bf16* __restrict__ Y0, bf16* __restrict__ Y1, bf16* __restrict__ Y2,
    const int* __restrict__ flag) {
  int z = blockIdx.z;
  const void* X = (z == 0) ? X0 : (z == 1) ? X1 : X2;
  bf16* Y       = (z == 0) ? Y0 : (z == 1) ? Y1 : Y2;
  size_t idx = ((size_t)blockIdx.x * 256 + threadIdx.x) * 8;
  if (*flag) *(bf16x8*)(Y + idx) = *(const bf16x8*)((const bf16*)X + idx);
  else       *(bf16x8*)(Y + idx) = ld8((const float*)X + idx);
}

// ---------------- fused weight transposes: Wt[n][k] = bf16(W[k][n]) ----------------
template<typename T>
__device__ __forceinline__ void tr_body(const T* __restrict__ W, bf16* __restrict__ Wt,
                                        bf16 (*t)[33]) {
  int tx = threadIdx.x, ty = threadIdx.y;            // block (32,8)
  int x = blockIdx.x * 32 + tx;
  for (int r = 0; r < 4; r++)
    t[ty + r * 8][tx] = to_b(W[(blockIdx.y * 32 + ty + r * 8) * EE + x]);
  __syncthreads();
  int x2 = blockIdx.y * 32 + tx;
  for (int r = 0; r < 4; r++)
    Wt[(blockIdx.x * 32 + ty + r * 8) * EE + x2] = t[tx][ty + r * 8];
}

__global__ __launch_bounds__(256) void transpose_w4(
    const void* __restrict__ W0, const void* __restrict__ W1,
    const void* __restrict__ W2, const void* __restrict__ W3,
    bf16* __restrict__ T0, bf16* __restrict__ T1,
    bf16* __restrict__ T2, bf16* __restrict__ T3,
    const int* __restrict__ flag) {
  __shared__ bf16 t[32][33];
  int z = blockIdx.z;
  const void* W = (z == 0) ? W0 : (z == 1) ? W1 : (z == 2) ? W2 : W3;
  bf16* Wt      = (z == 0) ? T0 : (z == 1) ? T1 : (z == 2) ? T2 : T3;
  if (*flag) tr_body<bf16>((const bf16*)W, Wt, t);
  else       tr_body<float>((const float*)W, Wt, t);
}

// ---------------- m97-style 128x128 GEMM, A bf16, Bt is [N][K] bf16 ----------------
// mode 0: C bf16 row-major [M][E] + bias
// mode 2: C bf16 [B,H,D,L] + bias (v transposed head layout)
// mode 3: C TIO row-major [M][E] + bias (final output)
template<typename TIO>
__device__ void gemm_body(const bf16* __restrict__ A, const bf16* __restrict__ Bt,
                          const TIO* __restrict__ bias, void* __restrict__ Cv,
                          int mode, bf16* As, bf16* Bs) {
  constexpr int K = EE;
  int tid = threadIdx.x;
  int lane = tid & 63, w = tid >> 6;
  int l16 = lane & 15, quad = lane >> 4;
  int m0 = blockIdx.y * 128;
  int n0 = blockIdx.x * 128;
  int mw = (w & 1) * 64;
  int nw = (w >> 1) * 64;
  int lr = lane >> 2;            // staging row within 16-row group
  int lc = (lane & 3) * 8;       // staging col (elements)

  f32x4 acc[4][4] = {};

  for (int k0 = 0; k0 < K; k0 += 32) {
    __syncthreads();
#pragma unroll
    for (int s = 0; s < 2; s++) {
      int r = w * 32 + s * 16;
      async16(A  + (size_t)(m0 + r + lr) * K + k0 + lc, As + r * 32);
      async16(Bt + (size_t)(n0 + r + lr) * K + k0 + lc, Bs + r * 32);
    }
    __syncthreads();   // drains vmcnt before barrier (m97)
    bf16x8 af[4], bfr[4];
#pragma unroll
    for (int t = 0; t < 4; t++) {
      af[t]  = *(const bf16x8*)(As + (mw + t * 16 + l16) * 32 + quad * 8);
      bfr[t] = *(const bf16x8*)(Bs + (nw + t * 16 + l16) * 32 + quad * 8);
    }
#pragma unroll
    for (int mt = 0; mt < 4; mt++)
#pragma unroll
      for (int nt = 0; nt < 4; nt++)
        acc[mt][nt] = __builtin_amdgcn_mfma_f32_16x16x32_bf16(af[mt], bfr[nt], acc[mt][nt], 0, 0, 0);
  }

#pragma unroll
  for (int nt = 0; nt < 4; nt++) {
    int col = n0 + nw + nt * 16 + l16;
    float bv = ldf(bias + col);
    int hh = col >> 6, d = col & 63;
#pragma unroll
    for (int mt = 0; mt < 4; mt++) {
      f32x4 v = acc[mt][nt];
      int rowb = m0 + mw + mt * 16 + quad * 4;
      if (mode == 0) {
#pragma unroll
        for (int i = 0; i < 4; i++)
          ((bf16*)Cv)[(size_t)(rowb + i) * EE + col] = __float2bfloat16(v[i] + bv);
      } else if (mode == 3) {
#pragma unroll
        for (int i = 0; i < 4; i++) {
          float val = v[i] + bv;
          if constexpr (__is_same(TIO, bf16))
            ((bf16*)Cv)[(size_t)(rowb + i) * EE + col] = __float2bfloat16(val);
          else
            ((float*)Cv)[(size_t)(rowb + i) * EE + col] = val;
        }
      } else {  // mode 2: V^T [B,H,D,L], 4 consecutive l -> 8B store
        int b = rowb >> 11, l0 = rowb & 2047;
        union { s16x4 p; bf16 e[4]; } u;
#pragma unroll
        for (int i = 0; i < 4; i++) u.e[i] = __float2bfloat16(v[i] + bv);
        *(s16x4*)((bf16*)Cv + ((size_t)(b * HH + hh) * DD + d) * LL + l0) = u.p;
      }
    }
  }
}

__global__ __launch_bounds__(256) void qkv_gemm(
    const bf16* __restrict__ Qc, const bf16* __restrict__ Kc, const bf16* __restrict__ Vc,
    const bf16* __restrict__ WQt, const bf16* __restrict__ WKt, const bf16* __restrict__ WVt,
    const void* __restrict__ bQ, const void* __restrict__ bK, const void* __restrict__ bV,
    bf16* __restrict__ qo, bf16* __restrict__ ko, bf16* __restrict__ vo,
    const int* __restrict__ flag) {
  __shared__ __align__(16) bf16 As[128 * 32];
  __shared__ __align__(16) bf16 Bs[128 * 32];
  int z = blockIdx.z;
  const bf16* A    = (z == 0) ? Qc  : (z == 1) ? Kc  : Vc;
  const bf16* Bt   = (z == 0) ? WQt : (z == 1) ? WKt : WVt;
  const void* bb   = (z == 0) ? bQ  : (z == 1) ? bK  : bV;
  bf16* C          = (z == 0) ? qo  : (z == 1) ? ko  : vo;
  int mode = (z == 2) ? 2 : 0;
  if (*flag) gemm_body<bf16>(A, Bt, (const bf16*)bb, C, mode, As, Bs);
  else       gemm_body<float>(A, Bt, (const float*)bb, C, mode, As, Bs);
}

__global__ __launch_bounds__(256) void out_gemm(const bf16* __restrict__ A,
                                                const bf16* __restrict__ WOt,
                                                const void* __restrict__ bO,
                                                void* __restrict__ C,
                                                const int* __restrict__ flag) {
  __shared__ __align__(16) bf16 As[128 * 32];
  __shared__ __align__(16) bf16 Bs[128 * 32];
  if (*flag) gemm_body<bf16>(A, WOt, (const bf16*)bO, C, 3, As, Bs);
  else       gemm_body<float>(A, WOt, (const float*)bO, C, 3, As, Bs);
}

// ---------------- flash attention, causal, S^T formulation + LDS double-buffer ----------------
// q,k: [B,L,E] bf16 (head offset h*64, row stride E)   v: [B,H,D,L] bf16   out: [B,L,E] bf16
// K/V^T 64-key tiles cooperatively staged via async16 into LDS with a 16B-block
// XOR swizzle (blk ^= row&7) to break the 128B-row 16-way bank conflict.
__global__ __launch_bounds__(256) void attn(const bf16* __restrict__ qg,
                                            const bf16* __restrict__ kg,
                                            const bf16* __restrict__ vg,
                                            bf16* __restrict__ outg) {
  __shared__ __align__(16) bf16 Ks[2][64 * 64];
  __shared__ __align__(16) bf16 Vs[2][64 * 64];
  int bh = blockIdx.y;
  int pb = blockIdx.x;               // handles tiles pb and 31-pb (causal load balance)
  int tid = threadIdx.x;
  int w = tid >> 6, lane = tid & 63, l16 = lane & 15, quad = lane >> 4;
  int b = bh >> 4, hh = bh & 15;

  const bf16* qp = qg + (size_t)b * LL * EE + hh * DD;
  const bf16* kp = kg + (size_t)b * LL * EE + hh * DD;
  const bf16* vp = vg + (size_t)bh * DD * LL;
  const f32x4 z4 = {};
  int x7 = l16 & 7;                  // read-side swizzle key (row&7 == l16&7 for our rows)

  for (int half = 0; half < 2; half++) {
    int tile = half ? (31 - pb) : pb;
    int qrow0 = tile * 64 + w * 16;
    int q = qrow0 + l16;
    bf16x8 bq0 = *(const bf16x8*)(qp + (size_t)q * EE + quad * 8);
    bf16x8 bq1 = *(const bf16x8*)(qp + (size_t)q * EE + 32 + quad * 8);

    float m = -1.0e30f, l = 0.f;
    f32x4 o[4] = {};
    int kend = tile + 1;             // uniform across the block's 4 waves

    __syncthreads();                 // protect buf0 from previous half's readers
    // prologue: stage tile kb=0 into buf 0
    {
      int kbase = 0;
#pragma unroll
      for (int t = 0; t < 2; t++) {
        int R = w * 16 + t * 8;
        int r = R + (lane >> 3);
        int gb = (lane & 7) ^ (r & 7);
        async16(kp + (size_t)(kbase + r) * EE + gb * 8, &Ks[0][R * 64]);
        async16(vp + (size_t)r * LL + kbase + gb * 8, &Vs[0][R * 64]);
      }
    }

    for (int kb = 0; kb < kend; kb++) {
      int kbase = kb * 64;
      __syncthreads();               // vmcnt drain: stage(kb) complete
      if (kb + 1 < kend) {           // prefetch next tile into other buffer
        int nb = (kb + 1) & 1;
        int nbase = kbase + 64;
#pragma unroll
        for (int t = 0; t < 2; t++) {
          int R = w * 16 + t * 8;
          int r = R + (lane >> 3);
          int gb = (lane & 7) ^ (r & 7);
          async16(kp + (size_t)(nbase + r) * EE + gb * 8, &Ks[nb][R * 64]);
          async16(vp + (size_t)r * LL + nbase + gb * 8, &Vs[nb][R * 64]);
        }
      }
      const bf16* Kb = &Ks[kb & 1][0];
      const bf16* Vb = &Vs[kb & 1][0];

      // ---- S^T = K·Q^T: A = K rows (from LDS), B = Q rows; C frag: row=key, col=q ----
      f32x4 s[4];
#pragma unroll
      for (int kt = 0; kt < 4; kt++) {
        int row = kt * 16 + l16;
        bf16x8 kf0 = *(const bf16x8*)(Kb + row * 64 + (quad ^ x7) * 8);
        bf16x8 kf1 = *(const bf16x8*)(Kb + row * 64 + ((quad + 4) ^ x7) * 8);
        s[kt] = __builtin_amdgcn_mfma_f32_16x16x32_bf16(kf0, bq0, z4, 0, 0, 0);
        s[kt] = __builtin_amdgcn_mfma_f32_16x16x32_bf16(kf1, bq1, s[kt], 0, 0, 0);
      }
#if __has_builtin(__builtin_amdgcn_mfma_f32_16x16x16bf16_1k)
      s16x4 vf[4][4];   // V^T A-frags: A[m=d=l16][k=key=quad*4+j]
#pragma unroll
      for (int j = 0; j < 4; j++)
#pragma unroll
        for (int kt = 0; kt < 4; kt++)
          vf[j][kt] = *(const s16x4*)(Vb + (j * 16 + l16) * 64 +
                                      ((kt * 2 + (quad >> 1)) ^ x7) * 8 + (quad & 1) * 4);
#endif
      // ---- mask + scale ----
      float sv[16];
      if (kbase + 63 <= qrow0) {
#pragma unroll
        for (int kt = 0; kt < 4; kt++)
#pragma unroll
          for (int i = 0; i < 4; i++) sv[kt * 4 + i] = s[kt][i] * SCL;
      } else {
        int rel = q - kbase - quad * 4;
#pragma unroll
        for (int kt = 0; kt < 4; kt++)
#pragma unroll
          for (int i = 0; i < 4; i++)
            sv[kt * 4 + i] = (kt * 16 + i <= rel) ? s[kt][i] * SCL : -1.0e30f;
      }
      // ---- online softmax (per lane = per q column; 2 cross-quad shuffles) ----
      float mloc = sv[0];
#pragma unroll
      for (int i = 1; i < 16; i++) mloc = fmaxf(mloc, sv[i]);
      mloc = fmaxf(mloc, __shfl_xor(mloc, 16));
      mloc = fmaxf(mloc, __shfl_xor(mloc, 32));
      float mnew = fmaxf(m, mloc);
      float alpha = exp2f((m - mnew) * L2E);
      float p[16], ssum = 0.f;
#pragma unroll
      for (int i = 0; i < 16; i++) { p[i] = exp2f((sv[i] - mnew) * L2E); ssum += p[i]; }
      ssum += __shfl_xor(ssum, 16);
      ssum += __shfl_xor(ssum, 32);
      l = l * alpha + ssum;
      m = mnew;
#pragma unroll
      for (int j = 0; j < 4; j++)
#pragma unroll
        for (int i = 0; i < 4; i++) o[j][i] *= alpha;
      // ---- P^T pack: C-layout == B-operand layout of 16x16x16 MFMA ----
      union { s16x4 v4; bf16 e[4]; unsigned u[2]; } pk[4];
#pragma unroll
      for (int kt = 0; kt < 4; kt++)
#pragma unroll
        for (int i = 0; i < 4; i++) pk[kt].e[i] = __float2bfloat16(p[kt * 4 + i]);
#if __has_builtin(__builtin_amdgcn_mfma_f32_16x16x16bf16_1k)
#pragma unroll
      for (int kt = 0; kt < 4; kt++)
#pragma unroll
        for (int j = 0; j < 4; j++)
          o[j] = __builtin_amdgcn_mfma_f32_16x16x16bf16_1k(vf[j][kt], pk[kt].v4, o[j], 0, 0, 0);
#else
#pragma unroll
      for (int c = 0; c < 2; c++) {
        union { bf16x8 v8; unsigned u[4]; } bfr;
#pragma unroll
        for (int r = 0; r < 4; r++) {
          int key = c * 32 + quad * 8 + 2 * r;
          int srcl = (((key >> 2) & 3) << 4) + l16;
          unsigned v0 = __shfl((int)pk[2 * c].u[r & 1], srcl, 64);
          unsigned v1 = __shfl((int)pk[2 * c + 1].u[r & 1], srcl, 64);
          bfr.u[r] = (quad < 2) ? v0 : v1;
        }
#pragma unroll
        for (int j = 0; j < 4; j++) {
          bf16x8 vfr = *(const bf16x8*)(Vb + (j * 16 + l16) * 64 + ((c * 4 + quad) ^ x7) * 8);
          o[j] = __builtin_amdgcn_mfma_f32_16x16x32_bf16(vfr, bfr.v8, o[j], 0, 0, 0);
        }
      }
#endif
    }
    // ---- epilogue: O^T frag (d = j*16+quad*4+i, q = l16), 8B packed stores ----
    float inv = 1.0f / l;
#pragma unroll
    for (int j = 0; j < 4; j++) {
      union { s16x4 v4; bf16 e[4]; } u;
#pragma unroll
      for (int i = 0; i < 4; i++) u.e[i] = __float2bfloat16(o[j][i] * inv);
      *(s16x4*)(outg + (size_t)(b * LL + q) * EE + hh * DD + j * 16 + quad * 4) = u.v4;
    }
  }
}

extern "C" void kernel_launch(void* const* d_in, const int* in_sizes, int n_in,
                              void* d_out, int out_size, void* d_ws, size_t ws_size,
                              hipStream_t stream) {
  const void* Q   = d_in[0];
  const void* Kin = d_in[1];
  const void* V   = d_in[2];
  const void* WQ  = d_in[3];
  const void* bQ  = d_in[4];
  const void* WK  = d_in[5];
  const void* bK  = d_in[6];
  const void* WV  = d_in[7];
  const void* bV  = d_in[8];
  const void* WO  = d_in[9];
  const void* bO  = d_in[10];

  int* flag = (int*)d_ws;
  bf16* base = (bf16*)((char*)d_ws + 256);
  bf16* wqt  = base;                        // 4 x 1024^2 bf16
  bf16* wkt  = wqt + (size_t)EE * EE;
  bf16* wvt  = wkt + (size_t)EE * EE;
  bf16* wot  = wvt + (size_t)EE * EE;
  bf16* Qc   = wot + (size_t)EE * EE;       // converted inputs, [B,L,E] bf16
  bf16* Kc   = Qc  + (size_t)MM * EE;
  bf16* Vc   = Kc  + (size_t)MM * EE;
  bf16* qws  = Vc  + (size_t)MM * EE;       // projected q  [B,L,E]
  bf16* kws  = qws + (size_t)MM * EE;       // projected k  [B,L,E]
  bf16* vws  = kws + (size_t)MM * EE;       // projected v  [B,H,D,L]
  bf16* aout = vws + (size_t)MM * EE;       // attention out [B,L,E]

  detect_dtype<<<1, 256, 0, stream>>>((const unsigned int*)WQ, flag);

  convert_in<<<dim3(MM * EE / 8 / 256, 1, 3), 256, 0, stream>>>(Q, Kin, V, Qc, Kc, Vc, flag);

  transpose_w4<<<dim3(32, 32, 4), dim3(32, 8), 0, stream>>>(
      WQ, WK, WV, WO, wqt, wkt, wvt, wot, flag);

  qkv_gemm<<<dim3(EE / 128, MM / 128, 3), 256, 0, stream>>>(
      Qc, Kc, Vc, wqt, wkt, wvt, bQ, bK, bV, qws, kws, vws, flag);

  attn<<<dim3(16, BB * HH), 256, 0, stream>>>(qws, kws, vws, aout);

  out_gemm<<<dim3(EE / 128, MM / 128), 256, 0, stream>>>(aout, wot, bO, d_out, flag);
}

// Round 6
// 436.189 us; speedup vs baseline: 2.0409x; 1.0401x over previous
//
#include <hip/hip_runtime.h>
#include <hip/hip_bf16.h>

#define BB 4
#define HH 16
#define LL 2048
#define DD 64
#define EE 1024
#define MM (BB*LL)   // 8192 rows
#define SCL 0.125f
#define L2E 1.44269504f

using bf16   = __hip_bfloat16;
using bf16x8 = __attribute__((ext_vector_type(8))) __bf16;
using s16x4  = __attribute__((ext_vector_type(4))) short;
using f32x4  = __attribute__((ext_vector_type(4))) float;
using u32x4  = __attribute__((ext_vector_type(4))) unsigned int;
typedef unsigned int u32;

// ---- dtype-polymorphic helpers (verified R2/R4) ----
__device__ __forceinline__ bf16x8 ld8(const bf16* p){ return *(const bf16x8*)p; }
__device__ __forceinline__ bf16x8 ld8(const float* p){
  u32x4 a = *(const u32x4*)p;
  u32x4 b = *(const u32x4*)(p + 4);
  union { bf16x8 v; unsigned short s[8]; } r;
#pragma unroll
  for (int i = 0; i < 4; i++) r.s[i]     = (unsigned short)((a[i] + 0x7FFFu + ((a[i] >> 16) & 1u)) >> 16);
#pragma unroll
  for (int i = 0; i < 4; i++) r.s[i + 4] = (unsigned short)((b[i] + 0x7FFFu + ((b[i] >> 16) & 1u)) >> 16);
  return r.v;
}
__device__ __forceinline__ float ldf(const bf16* p){ return __bfloat162float(*p); }
__device__ __forceinline__ float ldf(const float* p){ return *p; }
__device__ __forceinline__ bf16 to_b(bf16 v){ return v; }
__device__ __forceinline__ bf16 to_b(float v){ return __float2bfloat16(v); }

// async global->LDS, 16B/lane; LDS dest = wave-uniform base + lane*16 (m97/m104)
__device__ __forceinline__ void async16(const bf16* g, bf16* l) {
  __builtin_amdgcn_global_load_lds((const __attribute__((address_space(1))) u32*)g,
                                   (__attribute__((address_space(3))) u32*)l, 16, 0, 0);
}

// ---- dtype detect (verified R2/R4) ----
__global__ __launch_bounds__(256) void detect_dtype(const unsigned int* __restrict__ w,
                                                    int* __restrict__ flag) {
  __shared__ int cnt[256];
  int tid = threadIdx.x;
  int c = 0;
  for (int i = 0; i < 16; i++) {
    unsigned u = w[tid * 16 + i];
    unsigned e = (u >> 7) & 0xFF;
    c += (e >= 100 && e <= 140) ? 1 : 0;
  }
  cnt[tid] = c;
  __syncthreads();
  for (int s = 128; s > 0; s >>= 1) {
    if (tid < s) cnt[tid] += cnt[tid + s];
    __syncthreads();
  }
  if (tid == 0) *flag = (cnt[0] > 2048) ? 1 : 0;   // 1 = bf16 inputs
}

// ---- input pre-convert: Q/K/V -> bf16 workspace (copy if already bf16) ----
__global__ __launch_bounds__(256) void convert_in(
    const void* __restrict__ X0, const void* __restrict__ X1, const void* __restrict__ X2,
    bf16* __restrict__ Y0, bf16* __restrict__ Y1, bf16* __restrict__ Y2,
    const int* __restrict__ flag) {
  int z = blockIdx.z;
  const void* X = (z == 0) ? X0 : (z == 1) ? X1 : X2;
  bf16* Y       = (z == 0) ? Y0 : (z == 1) ? Y1 : Y2;
  size_t idx = ((size_t)blockIdx.x * 256 + threadIdx.x) * 8;
  if (*flag) *(bf16x8*)(Y + idx) = *(const bf16x8*)((const bf16*)X + idx);
  else       *(bf16x8*)(Y + idx) = ld8((const float*)X + idx);
}

// ---------------- fused weight transposes: Wt[n][k] = bf16(W[k][n]) ----------------
template<typename T>
__device__ __forceinline__ void tr_body(const T* __restrict__ W, bf16* __restrict__ Wt,
                                        bf16 (*t)[33]) {
  int tx = threadIdx.x, ty = threadIdx.y;            // block (32,8)
  int x = blockIdx.x * 32 + tx;
  for (int r = 0; r < 4; r++)
    t[ty + r * 8][tx] = to_b(W[(blockIdx.y * 32 + ty + r * 8) * EE + x]);
  __syncthreads();
  int x2 = blockIdx.y * 32 + tx;
  for (int r = 0; r < 4; r++)
    Wt[(blockIdx.x * 32 + ty + r * 8) * EE + x2] = t[tx][ty + r * 8];
}

__global__ __launch_bounds__(256) void transpose_w4(
    const void* __restrict__ W0, const void* __restrict__ W1,
    const void* __restrict__ W2, const void* __restrict__ W3,
    bf16* __restrict__ T0, bf16* __restrict__ T1,
    bf16* __restrict__ T2, bf16* __restrict__ T3,
    const int* __restrict__ flag) {
  __shared__ bf16 t[32][33];
  int z = blockIdx.z;
  const void* W = (z == 0) ? W0 : (z == 1) ? W1 : (z == 2) ? W2 : W3;
  bf16* Wt      = (z == 0) ? T0 : (z == 1) ? T1 : (z == 2) ? T2 : T3;
  if (*flag) tr_body<bf16>((const bf16*)W, Wt, t);
  else       tr_body<float>((const float*)W, Wt, t);
}

// ---------------- m97-style 128x128 GEMM, A bf16, Bt is [N][K] bf16 ----------------
// XCD-aware remap: dispatch linear id % 8 selects XCD (round-robin heuristic),
// so give each XCD 8 contiguous m-panels (A slice 2 MB -> L2-resident) x all n.
// mode 0: C bf16 row-major [M][E] + bias
// mode 2: C bf16 [B,H,D,L] + bias (v transposed head layout)
// mode 3: C TIO row-major [M][E] + bias (final output)
template<typename TIO>
__device__ void gemm_body(const bf16* __restrict__ A, const bf16* __restrict__ Bt,
                          const TIO* __restrict__ bias, void* __restrict__ Cv,
                          int mode, bf16* As, bf16* Bs) {
  constexpr int K = EE;
  int tid = threadIdx.x;
  int lane = tid & 63, w = tid >> 6;
  int l16 = lane & 15, quad = lane >> 4;
  int linear = blockIdx.x + 8 * blockIdx.y;      // grid (8,64[,z])
  int xcd = linear & 7;
  int slot = linear >> 3;
  int m0 = (xcd * 8 + (slot & 7)) * 128;         // m-tile
  int n0 = (slot >> 3) * 128;                    // n-tile
  int mw = (w & 1) * 64;
  int nw = (w >> 1) * 64;
  int lr = lane >> 2;            // staging row within 16-row group
  int lc = (lane & 3) * 8;       // staging col (elements)

  f32x4 acc[4][4] = {};

  for (int k0 = 0; k0 < K; k0 += 32) {
    __syncthreads();
#pragma unroll
    for (int s = 0; s < 2; s++) {
      int r = w * 32 + s * 16;
      async16(A  + (size_t)(m0 + r + lr) * K + k0 + lc, As + r * 32);
      async16(Bt + (size_t)(n0 + r + lr) * K + k0 + lc, Bs + r * 32);
    }
    __syncthreads();   // drains vmcnt before barrier (m97)
    bf16x8 af[4], bfr[4];
#pragma unroll
    for (int t = 0; t < 4; t++) {
      af[t]  = *(const bf16x8*)(As + (mw + t * 16 + l16) * 32 + quad * 8);
      bfr[t] = *(const bf16x8*)(Bs + (nw + t * 16 + l16) * 32 + quad * 8);
    }
#pragma unroll
    for (int mt = 0; mt < 4; mt++)
#pragma unroll
      for (int nt = 0; nt < 4; nt++)
        acc[mt][nt] = __builtin_amdgcn_mfma_f32_16x16x32_bf16(af[mt], bfr[nt], acc[mt][nt], 0, 0, 0);
  }

#pragma unroll
  for (int nt = 0; nt < 4; nt++) {
    int col = n0 + nw + nt * 16 + l16;
    float bv = ldf(bias + col);
    int hh = col >> 6, d = col & 63;
#pragma unroll
    for (int mt = 0; mt < 4; mt++) {
      f32x4 v = acc[mt][nt];
      int rowb = m0 + mw + mt * 16 + quad * 4;
      if (mode == 0) {
#pragma unroll
        for (int i = 0; i < 4; i++)
          ((bf16*)Cv)[(size_t)(rowb + i) * EE + col] = __float2bfloat16(v[i] + bv);
      } else if (mode == 3) {
#pragma unroll
        for (int i = 0; i < 4; i++) {
          float val = v[i] + bv;
          if constexpr (__is_same(TIO, bf16))
            ((bf16*)Cv)[(size_t)(rowb + i) * EE + col] = __float2bfloat16(val);
          else
            ((float*)Cv)[(size_t)(rowb + i) * EE + col] = val;
        }
      } else {  // mode 2: V^T [B,H,D,L], 4 consecutive l -> 8B store
        int b = rowb >> 11, l0 = rowb & 2047;
        union { s16x4 p; bf16 e[4]; } u;
#pragma unroll
        for (int i = 0; i < 4; i++) u.e[i] = __float2bfloat16(v[i] + bv);
        *(s16x4*)((bf16*)Cv + ((size_t)(b * HH + hh) * DD + d) * LL + l0) = u.p;
      }
    }
  }
}

__global__ __launch_bounds__(256) void qkv_gemm(
    const bf16* __restrict__ Qc, const bf16* __restrict__ Kc, const bf16* __restrict__ Vc,
    const bf16* __restrict__ WQt, const bf16* __restrict__ WKt, const bf16* __restrict__ WVt,
    const void* __restrict__ bQ, const void* __restrict__ bK, const void* __restrict__ bV,
    bf16* __restrict__ qo, bf16* __restrict__ ko, bf16* __restrict__ vo,
    const int* __restrict__ flag) {
  __shared__ __align__(16) bf16 As[128 * 32];
  __shared__ __align__(16) bf16 Bs[128 * 32];
  int z = blockIdx.z;
  const bf16* A    = (z == 0) ? Qc  : (z == 1) ? Kc  : Vc;
  const bf16* Bt   = (z == 0) ? WQt : (z == 1) ? WKt : WVt;
  const void* bb   = (z == 0) ? bQ  : (z == 1) ? bK  : bV;
  bf16* C          = (z == 0) ? qo  : (z == 1) ? ko  : vo;
  int mode = (z == 2) ? 2 : 0;
  if (*flag) gemm_body<bf16>(A, Bt, (const bf16*)bb, C, mode, As, Bs);
  else       gemm_body<float>(A, Bt, (const float*)bb, C, mode, As, Bs);
}

__global__ __launch_bounds__(256) void out_gemm(const bf16* __restrict__ A,
                                                const bf16* __restrict__ WOt,
                                                const void* __restrict__ bO,
                                                void* __restrict__ C,
                                                const int* __restrict__ flag) {
  __shared__ __align__(16) bf16 As[128 * 32];
  __shared__ __align__(16) bf16 Bs[128 * 32];
  if (*flag) gemm_body<bf16>(A, WOt, (const bf16*)bO, C, 3, As, Bs);
  else       gemm_body<float>(A, WOt, (const float*)bO, C, 3, As, Bs);
}

// ---------------- flash attention, causal, S^T formulation + LDS double-buffer ----------------
// q,k: [B,L,E] bf16 (head offset h*64, row stride E)   v: [B,H,D,L] bf16   out: [B,L,E] bf16
// XCD-aware remap: each XCD owns 8 whole heads (K+V working set ~4 MB = its L2).
__global__ __launch_bounds__(256) void attn(const bf16* __restrict__ qg,
                                            const bf16* __restrict__ kg,
                                            const bf16* __restrict__ vg,
                                            bf16* __restrict__ outg) {
  __shared__ __align__(16) bf16 Ks[2][64 * 64];
  __shared__ __align__(16) bf16 Vs[2][64 * 64];
  int linear = blockIdx.x + 16 * blockIdx.y;     // grid (16,64)
  int xcd = linear & 7;
  int slot = linear >> 3;                        // 0..127
  int bh = xcd * 8 + (slot & 7);                 // head-batch index, 8 per XCD
  int pb = slot >> 3;                            // 0..15; handles tiles pb and 31-pb
  int tid = threadIdx.x;
  int w = tid >> 6, lane = tid & 63, l16 = lane & 15, quad = lane >> 4;
  int b = bh >> 4, hh = bh & 15;

  const bf16* qp = qg + (size_t)b * LL * EE + hh * DD;
  const bf16* kp = kg + (size_t)b * LL * EE + hh * DD;
  const bf16* vp = vg + (size_t)bh * DD * LL;
  const f32x4 z4 = {};
  int x7 = l16 & 7;                  // read-side swizzle key (row&7 == l16&7 for our rows)

  for (int half = 0; half < 2; half++) {
    int tile = half ? (31 - pb) : pb;
    int qrow0 = tile * 64 + w * 16;
    int q = qrow0 + l16;
    bf16x8 bq0 = *(const bf16x8*)(qp + (size_t)q * EE + quad * 8);
    bf16x8 bq1 = *(const bf16x8*)(qp + (size_t)q * EE + 32 + quad * 8);

    float m = -1.0e30f, l = 0.f;
    f32x4 o[4] = {};
    int kend = tile + 1;             // uniform across the block's 4 waves

    __syncthreads();                 // protect buf0 from previous half's readers
    // prologue: stage tile kb=0 into buf 0
    {
      int kbase = 0;
#pragma unroll
      for (int t = 0; t < 2; t++) {
        int R = w * 16 + t * 8;
        int r = R + (lane >> 3);
        int gb = (lane & 7) ^ (r & 7);
        async16(kp + (size_t)(kbase + r) * EE + gb * 8, &Ks[0][R * 64]);
        async16(vp + (size_t)r * LL + kbase + gb * 8, &Vs[0][R * 64]);
      }
    }

    for (int kb = 0; kb < kend; kb++) {
      int kbase = kb * 64;
      __syncthreads();               // vmcnt drain: stage(kb) complete
      if (kb + 1 < kend) {           // prefetch next tile into other buffer
        int nb = (kb + 1) & 1;
        int nbase = kbase + 64;
#pragma unroll
        for (int t = 0; t < 2; t++) {
          int R = w * 16 + t * 8;
          int r = R + (lane >> 3);
          int gb = (lane & 7) ^ (r & 7);
          async16(kp + (size_t)(nbase + r) * EE + gb * 8, &Ks[nb][R * 64]);
          async16(vp + (size_t)r * LL + nbase + gb * 8, &Vs[nb][R * 64]);
        }
      }
      const bf16* Kb = &Ks[kb & 1][0];
      const bf16* Vb = &Vs[kb & 1][0];

      // ---- S^T = K·Q^T: A = K rows (from LDS), B = Q rows; C frag: row=key, col=q ----
      f32x4 s[4];
#pragma unroll
      for (int kt = 0; kt < 4; kt++) {
        int row = kt * 16 + l16;
        bf16x8 kf0 = *(const bf16x8*)(Kb + row * 64 + (quad ^ x7) * 8);
        bf16x8 kf1 = *(const bf16x8*)(Kb + row * 64 + ((quad + 4) ^ x7) * 8);
        s[kt] = __builtin_amdgcn_mfma_f32_16x16x32_bf16(kf0, bq0, z4, 0, 0, 0);
        s[kt] = __builtin_amdgcn_mfma_f32_16x16x32_bf16(kf1, bq1, s[kt], 0, 0, 0);
      }
#if __has_builtin(__builtin_amdgcn_mfma_f32_16x16x16bf16_1k)
      s16x4 vf[4][4];   // V^T A-frags: A[m=d=l16][k=key=quad*4+j]
#pragma unroll
      for (int j = 0; j < 4; j++)
#pragma unroll
        for (int kt = 0; kt < 4; kt++)
          vf[j][kt] = *(const s16x4*)(Vb + (j * 16 + l16) * 64 +
                                      ((kt * 2 + (quad >> 1)) ^ x7) * 8 + (quad & 1) * 4);
#endif
      // ---- mask + scale ----
      float sv[16];
      if (kbase + 63 <= qrow0) {
#pragma unroll
        for (int kt = 0; kt < 4; kt++)
#pragma unroll
          for (int i = 0; i < 4; i++) sv[kt * 4 + i] = s[kt][i] * SCL;
      } else {
        int rel = q - kbase - quad * 4;
#pragma unroll
        for (int kt = 0; kt < 4; kt++)
#pragma unroll
          for (int i = 0; i < 4; i++)
            sv[kt * 4 + i] = (kt * 16 + i <= rel) ? s[kt][i] * SCL : -1.0e30f;
      }
      // ---- online softmax (per lane = per q column; 2 cross-quad shuffles) ----
      float mloc = sv[0];
#pragma unroll
      for (int i = 1; i < 16; i++) mloc = fmaxf(mloc, sv[i]);
      mloc = fmaxf(mloc, __shfl_xor(mloc, 16));
      mloc = fmaxf(mloc, __shfl_xor(mloc, 32));
      float mnew = fmaxf(m, mloc);
      float alpha = exp2f((m - mnew) * L2E);
      float p[16], ssum = 0.f;
#pragma unroll
      for (int i = 0; i < 16; i++) { p[i] = exp2f((sv[i] - mnew) * L2E); ssum += p[i]; }
      ssum += __shfl_xor(ssum, 16);
      ssum += __shfl_xor(ssum, 32);
      l = l * alpha + ssum;
      m = mnew;
#pragma unroll
      for (int j = 0; j < 4; j++)
#pragma unroll
        for (int i = 0; i < 4; i++) o[j][i] *= alpha;
      // ---- P^T pack: C-layout == B-operand layout of 16x16x16 MFMA ----
      union { s16x4 v4; bf16 e[4]; unsigned u[2]; } pk[4];
#pragma unroll
      for (int kt = 0; kt < 4; kt++)
#pragma unroll
        for (int i = 0; i < 4; i++) pk[kt].e[i] = __float2bfloat16(p[kt * 4 + i]);
#if __has_builtin(__builtin_amdgcn_mfma_f32_16x16x16bf16_1k)
#pragma unroll
      for (int kt = 0; kt < 4; kt++)
#pragma unroll
        for (int j = 0; j < 4; j++)
          o[j] = __builtin_amdgcn_mfma_f32_16x16x16bf16_1k(vf[j][kt], pk[kt].v4, o[j], 0, 0, 0);
#else
#pragma unroll
      for (int c = 0; c < 2; c++) {
        union { bf16x8 v8; unsigned u[4]; } bfr;
#pragma unroll
        for (int r = 0; r < 4; r++) {
          int key = c * 32 + quad * 8 + 2 * r;
          int srcl = (((key >> 2) & 3) << 4) + l16;
          unsigned v0 = __shfl((int)pk[2 * c].u[r & 1], srcl, 64);
          unsigned v1 = __shfl((int)pk[2 * c + 1].u[r & 1], srcl, 64);
          bfr.u[r] = (quad < 2) ? v0 : v1;
        }
#pragma unroll
        for (int j = 0; j < 4; j++) {
          bf16x8 vfr = *(const bf16x8*)(Vb + (j * 16 + l16) * 64 + ((c * 4 + quad) ^ x7) * 8);
          o[j] = __builtin_amdgcn_mfma_f32_16x16x32_bf16(vfr, bfr.v8, o[j], 0, 0, 0);
        }
      }
#endif
    }
    // ---- epilogue: O^T frag (d = j*16+quad*4+i, q = l16), 8B packed stores ----
    float inv = 1.0f / l;
#pragma unroll
    for (int j = 0; j < 4; j++) {
      union { s16x4 v4; bf16 e[4]; } u;
#pragma unroll
      for (int i = 0; i < 4; i++) u.e[i] = __float2bfloat16(o[j][i] * inv);
      *(s16x4*)(outg + (size_t)(b * LL + q) * EE + hh * DD + j * 16 + quad * 4) = u.v4;
    }
  }
}

extern "C" void kernel_launch(void* const* d_in, const int* in_sizes, int n_in,
                              void* d_out, int out_size, void* d_ws, size_t ws_size,
                              hipStream_t stream) {
  const void* Q   = d_in[0];
  const void* Kin = d_in[1];
  const void* V   = d_in[2];
  const void* WQ  = d_in[3];
  const void* bQ  = d_in[4];
  const void* WK  = d_in[5];
  const void* bK  = d_in[6];
  const void* WV  = d_in[7];
  const void* bV  = d_in[8];
  const void* WO  = d_in[9];
  const void* bO  = d_in[10];

  int* flag = (int*)d_ws;
  bf16* base = (bf16*)((char*)d_ws + 256);
  bf16* wqt  = base;                        // 4 x 1024^2 bf16
  bf16* wkt  = wqt + (size_t)EE * EE;
  bf16* wvt  = wkt + (size_t)EE * EE;
  bf16* wot  = wvt + (size_t)EE * EE;
  bf16* Qc   = wot + (size_t)EE * EE;       // converted inputs, [B,L,E] bf16
  bf16* Kc   = Qc  + (size_t)MM * EE;
  bf16* Vc   = Kc  + (size_t)MM * EE;
  bf16* qws  = Vc  + (size_t)MM * EE;       // projected q  [B,L,E]
  bf16* kws  = qws + (size_t)MM * EE;       // projected k  [B,L,E]
  bf16* vws  = kws + (size_t)MM * EE;       // projected v  [B,H,D,L]
  bf16* aout = vws + (size_t)MM * EE;       // attention out [B,L,E]

  detect_dtype<<<1, 256, 0, stream>>>((const unsigned int*)WQ, flag);

  convert_in<<<dim3(MM * EE / 8 / 256, 1, 3), 256, 0, stream>>>(Q, Kin, V, Qc, Kc, Vc, flag);

  transpose_w4<<<dim3(32, 32, 4), dim3(32, 8), 0, stream>>>(
      WQ, WK, WV, WO, wqt, wkt, wvt, wot, flag);

  qkv_gemm<<<dim3(8, 64, 3), 256, 0, stream>>>(
      Qc, Kc, Vc, wqt, wkt, wvt, bQ, bK, bV, qws, kws, vws, flag);

  attn<<<dim3(16, 64), 256, 0, stream>>>(qws, kws, vws, aout);

  out_gemm<<<dim3(8, 64), 256, 0, stream>>>(aout, wot, bO, d_out, flag);
}